// Round 14
// baseline (517.668 us; speedup 1.0000x reference)
//
#include <hip/hip_runtime.h>
#include <math.h>

// ---------------------------------------------------------------------------
// XLSTMCell: gates = [x|h] @ W + b  (16384 x 5120 x 2048 GEMM, bf16 MFMA)
// R14: m97/m103 simple-structure family, conflict-free.
//   128x128 tile, BK=64, 256 thr (4 waves 2x2, 64x64/wave), SINGLE 32 KiB
//   LDS buffer, 2 __syncthreads per K-tile, NO manual waitcnt/setprio —
//   compiler schedules; 3-4 blocks/CU provide implicit cross-block overlap
//   (m114/m103: this structure measured 912 TF at 128^2 in learn_hip).
//   R1 (same skeleton) hit 822 TF WITH 1.26e8 16-way conflicts; here the
//   R4-verified pre-swizzled-global + XOR'd ds_read gives 0 conflicts.
//   XCD L3-blocking (R13-verified: FETCH 707->260 MB): XCD owns a disjoint
//   16-m-block slice x all 40 n0, n outer / m inner.
// ws layout: A_bf16[16384][2048] | Wt_bf16[5120][2048] | gates[16384][5120]
// ---------------------------------------------------------------------------

typedef unsigned short u16;
typedef unsigned int   u32;
typedef short  short8 __attribute__((ext_vector_type(8)));
typedef float  f32x4  __attribute__((ext_vector_type(4)));
typedef u16    u16x4  __attribute__((ext_vector_type(4)));
typedef u32    u32x4  __attribute__((ext_vector_type(4)));

#define B_ROWS 16384
#define K_DIM  2048
#define N_DIM  5120
#define H_DIM  1024

__device__ __forceinline__ float b2f(u16 u) {
    u32 v = ((u32)u) << 16;
    return __uint_as_float(v);
}
__device__ __forceinline__ u16 f2b(float f) {   // round-to-nearest-even
    u32 x = __float_as_uint(f);
    u32 r = (x + 0x7fffu + ((x >> 16) & 1u)) >> 16;
    return (u16)r;
}
__device__ __forceinline__ float sigm(float v) {
    return 1.f / (1.f + __expf(-v));
}
__device__ __forceinline__ float tanh_fast(float v) {
    v = fminf(fmaxf(v, -15.f), 15.f);
    float e = __expf(-2.f * v);
    return (1.f - e) / (1.f + e);
}

// ---------------------------------------------------------------------------
// 1) pack [x | h_prev] -> bf16 A [16384][2048], PRE-SWIZZLED:
//    granule slot s of each 64-elem K-window of row r holds granule s^(r&7).
// ---------------------------------------------------------------------------
__global__ __launch_bounds__(256) void convert_A(const float* __restrict__ x,
                                                 const float* __restrict__ h,
                                                 u16* __restrict__ A) {
    size_t idx = ((size_t)blockIdx.x * 256 + threadIdx.x) * 8;   // out elem idx
    int row = (int)(idx >> 11);
    int col = (int)(idx & 2047);                 // granule-aligned (col%8==0)
    int srcCol = (col & ~63) | (((((col >> 3) & 7) ^ (row & 7))) << 3);
    const float* src = (srcCol < 1024) ? (x + (size_t)row * 1024 + srcCol)
                                       : (h + (size_t)row * 1024 + (srcCol - 1024));
    f32x4 v0 = *(const f32x4*)src;
    f32x4 v1 = *(const f32x4*)(src + 4);
    u32x4 w;
    w.x = (u32)f2b(v0.x) | ((u32)f2b(v0.y) << 16);
    w.y = (u32)f2b(v0.z) | ((u32)f2b(v0.w) << 16);
    w.z = (u32)f2b(v1.x) | ((u32)f2b(v1.y) << 16);
    w.w = (u32)f2b(v1.z) | ((u32)f2b(v1.w) << 16);
    *(u32x4*)(A + idx) = w;
}

// ---------------------------------------------------------------------------
// 2) W [2048][5120] f32 -> Wt [5120][2048] bf16, transposed + PRE-SWIZZLED
//    (same granule rule, keyed by n-row & 7).
// ---------------------------------------------------------------------------
__global__ __launch_bounds__(256) void convert_W(const float* __restrict__ W,
                                                 u16* __restrict__ Wt) {
    __shared__ float tile[64][33];      // [k][n]
    const int t  = threadIdx.x;
    const int tx = t & 31;              // n
    const int ty = t >> 5;              // 0..7 (k)
    const int n0 = blockIdx.x * 32;     // 160 blocks
    const int k0 = blockIdx.y * 64;     // 32 blocks
#pragma unroll
    for (int i = 0; i < 8; ++i)
        tile[ty + 8 * i][tx] = W[(size_t)(k0 + ty + 8 * i) * N_DIM + n0 + tx];
    __syncthreads();
    const int n = t >> 3;               // 0..31
    const int s = t & 7;                // output granule slot
    const int g = s ^ (n & 7);          // source granule ((n0+n)&7 == n&7)
    u32x4 w;
    w.x = (u32)f2b(tile[g * 8 + 0][n]) | ((u32)f2b(tile[g * 8 + 1][n]) << 16);
    w.y = (u32)f2b(tile[g * 8 + 2][n]) | ((u32)f2b(tile[g * 8 + 3][n]) << 16);
    w.z = (u32)f2b(tile[g * 8 + 4][n]) | ((u32)f2b(tile[g * 8 + 5][n]) << 16);
    w.w = (u32)f2b(tile[g * 8 + 6][n]) | ((u32)f2b(tile[g * 8 + 7][n]) << 16);
    *(u32x4*)(Wt + (size_t)(n0 + n) * K_DIM + k0 + s * 8) = w;
}

// ---------------------------------------------------------------------------
// 3) GEMM: 128x128, BK=64, 256 thr (4 waves 2x2), single-buffer m97 loop.
//    Swizzle consistency: stage writes LDS row (i*32 + t>>3), slot t&7;
//    global source row has (row&7) == (t>>3)&7 == (LDS row)&7, and convert_*
//    stored granule g at slot g^(row&7). Read: lane wants k-granule
//    (sk*4+lh) -> reads slot (sk*4+lh)^z where z = lr&7 = (read row)&7. OK.
//    Bank check: 8 lanes/granule-slot group, slots spread by lh^z -> all 32
//    banks covered per 8-lane group -> conflict-free b128 (0 conflicts
//    measured with identical mapping, R4/R5/R11-R13).
// ---------------------------------------------------------------------------
#define BK 64

__device__ __forceinline__ void gld_lds16(const void* g, void* l) {
    __builtin_amdgcn_global_load_lds(
        (const __attribute__((address_space(1))) void*)g,
        (__attribute__((address_space(3))) void*)l, 16, 0, 0);   // offset MUST be 0
}

__global__ __launch_bounds__(256) void gemm_gates(const u16* __restrict__ A,
                                                  const u16* __restrict__ Bt,
                                                  const float* __restrict__ bias,
                                                  u16* __restrict__ gates) {
    __shared__ u16 As[128 * BK];          // 16 KiB
    __shared__ u16 Bs[128 * BK];          // 16 KiB

    const int t = threadIdx.x;
    // XCD L3-blocking: nwg = 5120 (%8==0). XCD x owns m-blocks 16x..16x+15,
    // all 40 n0; n outer, m inner (Wt 512KB panel L2-resident across the 16
    // consecutive blocks; A slice 8MB L3-resident, fetched once).
    const int bid = blockIdx.x;
    const int xcd = bid & 7;
    const int c   = bid >> 3;             // 0..639
    const int m0 = ((xcd << 4) | (c & 15)) << 7;  // 128 m-blocks of 128 rows
    const int n0 = (c >> 4) << 7;                 // 40 n-blocks of 128 cols

    const int l   = t & 63;
    const int wid = t >> 6;               // 0..3
    const int wm  = (wid >> 1) << 6;      // 0 / 64
    const int wn  = (wid & 1) << 6;       // 0 / 64
    const int lr  = l & 15;
    const int lh  = l >> 4;
    const int z   = lr & 7;
    const int sA0 = (lh ^ z) * 8;         // sk=0 granule slot offset (u16)

    // staging: thread t -> row t>>3 (0..31) of each 32-row stripe, slot t&7
    const int tb = t >> 3;
    const u16* aPtr = A  + (size_t)(m0 + tb) * K_DIM + (t & 7) * 8;
    const u16* bPtr = Bt + (size_t)(n0 + tb) * K_DIM + (t & 7) * 8;
    const int dOff = t * 8;               // u16

    f32x4 acc[4][4] = {};

#pragma unroll 1
    for (int kt = 0; kt < 32; ++kt) {
#pragma unroll
        for (int i = 0; i < 4; ++i) {
            gld_lds16(aPtr + (size_t)(i * 32) * K_DIM, &As[i * 2048 + dOff]);
            gld_lds16(bPtr + (size_t)(i * 32) * K_DIM, &Bs[i * 2048 + dOff]);
        }
        __syncthreads();                  // compiler drains vmcnt before bar

        short8 af[4][2], bf[4][2];
#pragma unroll
        for (int m = 0; m < 4; ++m) {
            const int u = (wm + m * 16 + lr) * 64;
            af[m][0] = *(const short8*)&As[u + sA0];
            af[m][1] = *(const short8*)&As[u + (sA0 ^ 32)];
        }
#pragma unroll
        for (int n = 0; n < 4; ++n) {
            const int u = (wn + n * 16 + lr) * 64;
            bf[n][0] = *(const short8*)&Bs[u + sA0];
            bf[n][1] = *(const short8*)&Bs[u + (sA0 ^ 32)];
        }
#pragma unroll
        for (int sk = 0; sk < 2; ++sk)
#pragma unroll
            for (int m = 0; m < 4; ++m)
#pragma unroll
                for (int n = 0; n < 4; ++n)
                    acc[m][n] = __builtin_amdgcn_mfma_f32_16x16x32_bf16(
                        af[m][sk], bf[n][sk], acc[m][n], 0, 0, 0);
        __syncthreads();
        aPtr += BK;
        bPtr += BK;
    }

    // epilogue: bias + activation (block's N-tile lies in one gate group)
    const int grp = n0 >> 10;             // 0..4 : f,i,o,c,m
#pragma unroll
    for (int ni = 0; ni < 4; ++ni) {
        int col = n0 + wn + ni * 16 + lr;
        float bv = bias[col];
#pragma unroll
        for (int mi = 0; mi < 4; ++mi) {
#pragma unroll
            for (int j = 0; j < 4; ++j) {
                int row = m0 + wm + mi * 16 + lh * 4 + j;
                float v = acc[mi][ni][j] + bv;
                float g = (grp == 3) ? tanh_fast(v) : sigm(v);
                gates[(size_t)row * N_DIM + col] = f2b(g);
            }
        }
    }
}

// ---------------------------------------------------------------------------
// 4) per-row: LN stats over o, cell update, outputs
// ---------------------------------------------------------------------------
__global__ __launch_bounds__(256) void fuse_out(const u16* __restrict__ gates,
                                                const float* __restrict__ c_prev,
                                                const float* __restrict__ ret,
                                                const float* __restrict__ gamma,
                                                const float* __restrict__ beta,
                                                float* __restrict__ out) {
    const int r = blockIdx.x;
    const int t = threadIdx.x;
    const u16* g = gates + (size_t)r * N_DIM;
    const int j0 = t * 4;

    // o = sigmoid(o_pre) already; LN stats over the row of 1024
    u16x4 ov = *(const u16x4*)(g + 2048 + j0);
    float o0 = b2f(ov.x), o1 = b2f(ov.y), o2 = b2f(ov.z), o3 = b2f(ov.w);
    float s1 = o0 + o1 + o2 + o3;
    float s2 = o0 * o0 + o1 * o1 + o2 * o2 + o3 * o3;
#pragma unroll
    for (int off = 32; off; off >>= 1) {
        s1 += __shfl_xor(s1, off, 64);
        s2 += __shfl_xor(s2, off, 64);
    }
    __shared__ float red[8];
    if ((t & 63) == 0) { red[t >> 6] = s1; red[4 + (t >> 6)] = s2; }
    __syncthreads();
    float S1 = red[0] + red[1] + red[2] + red[3];
    float S2 = red[4] + red[5] + red[6] + red[7];
    float mu   = S1 * (1.f / 1024.f);
    float var  = S2 * (1.f / 1024.f) - mu * mu;
    float rstd = rsqrtf(var + 1e-5f);

    u16x4 fv = *(const u16x4*)(g + j0);
    u16x4 iv = *(const u16x4*)(g + 1024 + j0);
    u16x4 cv = *(const u16x4*)(g + 3072 + j0);
    u16x4 mv = *(const u16x4*)(g + 4096 + j0);
    f32x4 cp = *(const f32x4*)(c_prev + (size_t)r * H_DIM + j0);
    f32x4 rt = *(const f32x4*)(ret + j0);
    f32x4 gm = *(const f32x4*)(gamma + j0);
    f32x4 bt = *(const f32x4*)(beta + j0);

    float of[4] = {o0, o1, o2, o3};
    u16 fa[4] = {fv.x, fv.y, fv.z, fv.w};
    u16 ia[4] = {iv.x, iv.y, iv.z, iv.w};
    u16 ca[4] = {cv.x, cv.y, cv.z, cv.w};
    u16 ma[4] = {mv.x, mv.y, mv.z, mv.w};

    f32x4 hout, cout;
#pragma unroll
    for (int i = 0; i < 4; ++i) {
        float f = b2f(fa[i]), ig = b2f(ia[i]), cc = b2f(ca[i]), m = b2f(ma[i]);
        float cpv = cp[i], rv = rt[i];
        float c1 = f * cpv + ig * cc;
        float c2 = c1 * rv + (1.f - rv) * cpv;
        float cn = m * c2 + (1.f - m) * cpv;
        float ln = (of[i] - mu) * rstd * gm[i] + bt[i];
        float oe = sigm(ln);
        float hn = oe * tanh_fast(cn);
        hout[i] = hn;
        cout[i] = cn;
    }
    *(f32x4*)(out + (size_t)r * H_DIM + j0) = hout;
    *(f32x4*)(out + (size_t)B_ROWS * H_DIM + (size_t)r * H_DIM + j0) = cout;
}

// ---------------------------------------------------------------------------
extern "C" void kernel_launch(void* const* d_in, const int* in_sizes, int n_in,
                              void* d_out, int out_size, void* d_ws, size_t ws_size,
                              hipStream_t stream) {
    const float* x      = (const float*)d_in[0];
    const float* h_prev = (const float*)d_in[1];
    const float* c_prev = (const float*)d_in[2];
    const float* W      = (const float*)d_in[3];
    const float* bias   = (const float*)d_in[4];
    const float* gamma  = (const float*)d_in[5];
    const float* beta   = (const float*)d_in[6];
    const float* ret    = (const float*)d_in[7];
    float* out = (float*)d_out;

    u16* Abuf  = (u16*)d_ws;                             // [16384][2048]
    u16* Wt    = Abuf + (size_t)B_ROWS * K_DIM;          // [5120][2048]
    u16* gates = Wt + (size_t)N_DIM * K_DIM;             // [16384][5120]

    convert_A<<<(B_ROWS * K_DIM / 8) / 256, 256, 0, stream>>>(x, h_prev, Abuf);
    convert_W<<<dim3(N_DIM / 32, K_DIM / 64), 256, 0, stream>>>(W, Wt);
    gemm_gates<<<(B_ROWS / 128) * (N_DIM / 128), 256, 0, stream>>>(Abuf, Wt, bias, gates);
    fuse_out<<<B_ROWS, 256, 0, stream>>>(gates, c_prev, ret, gamma, beta, out);
}